// Round 12
// baseline (208.152 us; speedup 1.0000x reference)
//
#include <hip/hip_runtime.h>

#define HH_ 128
#define WW_ 128
#define CC_ 128
#define P2 64
#define W2 256
#define NH 8
#define CH 16
#define NV 2
#define TOPK 4
#define SCALE 0.08838834764831845f  // 128^-0.5
#define SCALE_L2E 0.1275216f        // SCALE * log2(e)
#define CLAMP_L2 28.8539f           // 20 * log2(e)

typedef unsigned short u16;
typedef unsigned int   u32;
typedef short s8v __attribute__((ext_vector_type(8)));   // 8 bf16 (4 VGPR)
typedef float f4  __attribute__((ext_vector_type(4)));

#if __has_builtin(__builtin_amdgcn_exp2f)
#define EXP2(x) __builtin_amdgcn_exp2f(x)
#else
#define EXP2(x) exp2f(x)
#endif

union FRAG { uint4 q; u32 u[4]; s8v v; };

__device__ float g_means[(P2 + NV * P2) * CC_];
__device__ int2  g_part[64];   // fallback path: detector per-block partials

__device__ inline u16 f2b(float v) {
    union { float f; u32 u; } x; x.f = v;
    u32 r = x.u + 0x7FFFu + ((x.u >> 16) & 1u);
    return (u16)(r >> 16);
}
__device__ inline float b2f(u16 h) {
    union { u32 u; float f; } x; x.u = (u32)h << 16; return x.f;
}
__device__ inline float h2f(u16 h) {
    u32 s = (h >> 15) & 1u, e = (h >> 10) & 31u, m = h & 1023u;
    float v;
    if (e == 0)       v = m * 5.9604644775e-8f;
    else if (e == 31) v = 65504.f;
    else { union { u32 u; float f; } x; x.u = ((e + 112u) << 23) | (m << 13); v = x.f; }
    return s ? -v : v;
}
__device__ inline u16 f2h(float v) {
    union { float f; u32 u; } x; x.f = v;
    u32 s = (x.u >> 16) & 0x8000u;
    int  e = (int)((x.u >> 23) & 0xFF) - 112;
    u32  m = x.u & 0x7FFFFF;
    if (e >= 31) return (u16)(s | 0x7BFF);
    if (e <= 0) {
        if (e < -10) return (u16)s;
        m |= 0x800000u;
        int sh = 14 - e;
        u32 r = m >> sh, rem = m & ((1u << sh) - 1u), half = 1u << (sh - 1);
        if (rem > half || (rem == half && (r & 1))) r++;
        return (u16)(s | r);
    }
    u32 r = ((u32)e << 10) | (m >> 13), rem = m & 0x1FFFu;
    if (rem > 0x1000u || (rem == 0x1000u && (r & 1))) r++;
    return (u16)(s | r);
}

// ---- truncation-based bf16 split helpers ----
__device__ inline u32 pkhi(float a, float b) {
    union { float f; u32 u; } xa, xb; xa.f = a; xb.f = b;
    return (xa.u >> 16) | (xb.u & 0xFFFF0000u);
}
__device__ inline float hipart(float a) {
    union { float f; u32 u; } x; x.f = a; x.u &= 0xFFFF0000u; return x.f;
}

// fallback-path mode decision from g_part
__device__ inline int mode_from_parts() {
    int c0 = 0, c1 = 0;
#pragma unroll 8
    for (int k = 0; k < 64; ++k) { int2 v = g_part[k]; c0 += v.x; c1 += v.y; }
    const float T = 256.f * 64.f;
    float f0 = c0 / T, f1 = c1 / T;
    if (f1 >= 0.85f) return 1;
    if (f0 >= 0.80f) return 0;
    return 2;
}

template<int MODE>
__device__ inline float decode1(const void* __restrict__ src, int off) {
    if (MODE == 0) return ((const float*)src)[off];
    u16 h = ((const u16*)src)[off];
    return (MODE == 1) ? b2f(h) : h2f(h);
}

template<int MODE>
__device__ inline float4 loadf4(const void* __restrict__ src, int off) {
    if (MODE == 0) return *(const float4*)((const float*)src + off);
    uint2 v = *(const uint2*)((const u16*)src + off);
    float4 r;
    if (MODE == 1) {
        r.x = b2f((u16)v.x); r.y = b2f((u16)(v.x >> 16));
        r.z = b2f((u16)v.y); r.w = b2f((u16)(v.y >> 16));
    } else {
        r.x = h2f((u16)v.x); r.y = h2f((u16)(v.x >> 16));
        r.z = h2f((u16)v.y); r.w = h2f((u16)(v.y >> 16));
    }
    return r;
}

template<int MODE>
__device__ inline void store4t(void* __restrict__ out, int off, const float* __restrict__ r) {
    if (MODE == 0) {
        *(float4*)((float*)out + off) = make_float4(r[0], r[1], r[2], r[3]);
    } else if (MODE == 1) {
        u32 w0 = (u32)f2b(r[0]) | ((u32)f2b(r[1]) << 16);
        u32 w1 = (u32)f2b(r[2]) | ((u32)f2b(r[3]) << 16);
        *(uint2*)((u16*)out + off) = make_uint2(w0, w1);
    } else {
        u32 w0 = (u32)f2h(r[0]) | ((u32)f2h(r[1]) << 16);
        u32 w1 = (u32)f2h(r[2]) | ((u32)f2h(r[3]) << 16);
        *(uint2*)((u16*)out + off) = make_uint2(w0, w1);
    }
}

// ================= shared attention body (round-10 verified) =================
template<int MODE>
__device__ void attn_body(const void* __restrict__ cv, const void* __restrict__ mv,
                          void* __restrict__ out, int p, int m, int tid,
                          u32 (* __restrict__ kfrag)[64][4],
                          u32 (* __restrict__ vfrag)[64][4],
                          const int* __restrict__ rwin) {
    int jj = p >> 3, ii = p & 7;
    int wv = tid >> 6, l = tid & 63;
    int kh = wv >> 3, qs = wv & 7;
    int lg = l >> 4, lr = l & 15;

    // Q fragments for this q-slot's 2 qtiles (both slot orderings), * SCALE*log2e
    FRAG qf1[2], qf2[2];
#pragma unroll
    for (int qi = 0; qi < 2; ++qi) {
        int qrow = qs * 32 + qi * 16 + lr;
        int hh = qrow >> 4, ww = qrow & 15;
        int pix = (jj * 16 + hh) * WW_ + (ii * 16 + ww);
        float4 qv = loadf4<MODE>(cv, pix * CC_ + m * CH + 4 * lg);
        float q0 = qv.x * SCALE_L2E, q1 = qv.y * SCALE_L2E;
        float q2 = qv.z * SCALE_L2E, q3 = qv.w * SCALE_L2E;
        u32 h01 = pkhi(q0, q1), h23 = pkhi(q2, q3);
        u32 l01 = pkhi(q0 - hipart(q0), q1 - hipart(q1));
        u32 l23 = pkhi(q2 - hipart(q2), q3 - hipart(q3));
        qf1[qi].u[0] = h01; qf1[qi].u[1] = h23; qf1[qi].u[2] = l01; qf1[qi].u[3] = l23;
        qf2[qi].u[0] = l01; qf2[qi].u[1] = l23; qf2[qi].u[2] = h01; qf2[qi].u[3] = h23;
    }

    // stage round r (2 windows, 32 tiles, 2048 slots): load->pack->write per slot
    auto stage = [&](int r) {
#pragma unroll
        for (int i = 0; i < 2; ++i) {
            int s = tid + i * 1024;
            int tl = s >> 6, sl = s & 63;
            int slg = sl >> 4, slr = sl & 15;
            int t = rwin[2 * r + (tl >> 4)];
            int v = t >> 6, pp = t & 63;
            int jj2 = pp >> 3, ii2 = pp & 7;
            int wrow = (v * HH_ + jj2 * 16 + (tl & 15)) * WW_ + ii2 * 16;
            {
                float4 kc = loadf4<MODE>(mv, (wrow + slr) * CC_ + m * CH + 4 * slg);
                FRAG kf;
                kf.u[0] = pkhi(kc.x, kc.y);
                kf.u[1] = pkhi(kc.z, kc.w);
                kf.u[2] = pkhi(kc.x - hipart(kc.x), kc.y - hipart(kc.y));
                kf.u[3] = pkhi(kc.z - hipart(kc.z), kc.w - hipart(kc.w));
                *(uint4*)&kfrag[tl][sl][0] = kf.q;
            }
            {
                int a = (wrow + 4 * slg) * CC_ + m * CH + slr;
                float v0 = decode1<MODE>(mv, a);
                float v1 = decode1<MODE>(mv, a + CC_);
                float v2 = decode1<MODE>(mv, a + 2 * CC_);
                float v3 = decode1<MODE>(mv, a + 3 * CC_);
                FRAG vf;
                vf.u[0] = pkhi(v0, v1);
                vf.u[1] = pkhi(v2, v3);
                vf.u[2] = pkhi(v0 - hipart(v0), v1 - hipart(v1));
                vf.u[3] = pkhi(v2 - hipart(v2), v3 - hipart(v3));
                *(uint4*)&vfrag[tl][sl][0] = vf.q;
            }
        }
    };

    f4 Oacc0 = {0.f, 0.f, 0.f, 0.f};
    f4 Oacc1 = {0.f, 0.f, 0.f, 0.f};
    float lp0 = 0.f, lp1 = 0.f;
    const uint4* kp = (const uint4*)&kfrag[kh * 16][0][0] + l;  // loop-invariant
    const uint4* vp = (const uint4*)&vfrag[kh * 16][0][0] + l;

    auto computeh = [&]() {
#pragma unroll 4
        for (int tl = 0; tl < 16; ++tl) {
            FRAG kf, vf;
            kf.q = kp[tl * 64];
            vf.q = vp[tl * 64];
            // qtile 0
            {
                f4 sc = {0.f, 0.f, 0.f, 0.f};
                sc = __builtin_amdgcn_mfma_f32_16x16x32_bf16(kf.v, qf1[0].v, sc, 0, 0, 0);
                sc = __builtin_amdgcn_mfma_f32_16x16x32_bf16(kf.v, qf2[0].v, sc, 0, 0, 0);
                float pe0 = EXP2(fminf(sc[0], CLAMP_L2));
                float pe1 = EXP2(fminf(sc[1], CLAMP_L2));
                float pe2 = EXP2(fminf(sc[2], CLAMP_L2));
                float pe3 = EXP2(fminf(sc[3], CLAMP_L2));
                lp0 += (hipart(pe0) + hipart(pe1)) + (hipart(pe2) + hipart(pe3));
                FRAG pf;
                pf.u[0] = pkhi(pe0, pe1);
                pf.u[1] = pkhi(pe2, pe3);
                pf.u[2] = pf.u[0];
                pf.u[3] = pf.u[1];
                Oacc0 = __builtin_amdgcn_mfma_f32_16x16x32_bf16(vf.v, pf.v, Oacc0, 0, 0, 0);
            }
            // qtile 1
            {
                f4 sc = {0.f, 0.f, 0.f, 0.f};
                sc = __builtin_amdgcn_mfma_f32_16x16x32_bf16(kf.v, qf1[1].v, sc, 0, 0, 0);
                sc = __builtin_amdgcn_mfma_f32_16x16x32_bf16(kf.v, qf2[1].v, sc, 0, 0, 0);
                float pe0 = EXP2(fminf(sc[0], CLAMP_L2));
                float pe1 = EXP2(fminf(sc[1], CLAMP_L2));
                float pe2 = EXP2(fminf(sc[2], CLAMP_L2));
                float pe3 = EXP2(fminf(sc[3], CLAMP_L2));
                lp1 += (hipart(pe0) + hipart(pe1)) + (hipart(pe2) + hipart(pe3));
                FRAG pf;
                pf.u[0] = pkhi(pe0, pe1);
                pf.u[1] = pkhi(pe2, pe3);
                pf.u[2] = pf.u[0];
                pf.u[3] = pf.u[1];
                Oacc1 = __builtin_amdgcn_mfma_f32_16x16x32_bf16(vf.v, pf.v, Oacc1, 0, 0, 0);
            }
        }
    };

    // two rounds, plain barriers; TLP (32 waves/CU) hides stage latency
    stage(0);
    __syncthreads();
    computeh();
    __syncthreads();
    stage(1);
    __syncthreads();
    computeh();
    __syncthreads();   // done reading frags; kfrag is repurposed below

    // cross-kh combine through freed kfrag buffer: [qs][l][10] floats
    float* comb = (float*)&kfrag[0][0][0];
    int ci = (qs * 64 + l) * 10;
    if (kh == 1) {
#pragma unroll
        for (int r = 0; r < 4; ++r) { comb[ci + r] = Oacc0[r]; comb[ci + 4 + r] = Oacc1[r]; }
        comb[ci + 8] = lp0;
        comb[ci + 9] = lp1;
    }
    __syncthreads();
    if (kh == 0) {
#pragma unroll
        for (int r = 0; r < 4; ++r) { Oacc0[r] += comb[ci + r]; Oacc1[r] += comb[ci + 4 + r]; }
        lp0 += comb[ci + 8];
        lp1 += comb[ci + 9];
#pragma unroll
        for (int qi = 0; qi < 2; ++qi) {
            float lt = (qi == 0) ? lp0 : lp1;
            lt += __shfl_xor(lt, 16);
            lt += __shfl_xor(lt, 32);
            float inv = 1.0f / fmaxf(lt, 1e-30f);
            f4 Oa = (qi == 0) ? Oacc0 : Oacc1;
            float res[4];
#pragma unroll
            for (int r = 0; r < 4; ++r)
                res[r] = fminf(fmaxf(Oa[r] * inv, -1000.f), 1000.f);
            int qrow = qs * 32 + qi * 16 + lr;
            int hh = qrow >> 4, ww = qrow & 15;
            int pix = (jj * 16 + hh) * WW_ + (ii * 16 + ww);
            store4t<MODE>(out, pix * CC_ + m * CH + 4 * lg, res);
        }
    }
}

// win_mean row computation with 1024 threads (fused path)
template<int MODE>
__device__ inline void wm_row(const void* __restrict__ cv, const void* __restrict__ mv,
                              int row, int tid, float (* __restrict__ wmpart)[128]) {
    int o = tid & 15, pc = tid >> 4;   // pc 0..63: 4 pixels each; o: 8-ch slice
    const void* src; int voff = 0; int p;
    if (row < P2) { p = row; src = cv; }
    else { int r = row - P2; voff = (r >> 6) * HH_ * WW_ * CC_; p = r & 63; src = mv; }
    int jj = p >> 3, ii = p & 7;
    int c0 = 8 * o;
    float acc[8];
#pragma unroll
    for (int j = 0; j < 8; ++j) acc[j] = 0.f;
#pragma unroll
    for (int k = 0; k < 4; ++k) {
        int px = 4 * pc + k;
        int hh = px >> 4, ww = px & 15;
        int a = voff + ((jj * 16 + hh) * WW_ + ii * 16 + ww) * CC_ + c0;
        if (MODE == 0) {
            const float4* p4 = (const float4*)((const float*)src + a);
            float4 x = p4[0], y = p4[1];
            acc[0] += x.x; acc[1] += x.y; acc[2] += x.z; acc[3] += x.w;
            acc[4] += y.x; acc[5] += y.y; acc[6] += y.z; acc[7] += y.w;
        } else {
            uint4 v = *(const uint4*)((const u16*)src + a);
            u32 wd[4] = { v.x, v.y, v.z, v.w };
#pragma unroll
            for (int j = 0; j < 4; ++j) {
                u16 lo = (u16)(wd[j] & 0xFFFFu), hi = (u16)(wd[j] >> 16);
                acc[2 * j]     += (MODE == 1) ? b2f(lo) : h2f(lo);
                acc[2 * j + 1] += (MODE == 1) ? b2f(hi) : h2f(hi);
            }
        }
    }
#pragma unroll
    for (int j = 0; j < 8; ++j) wmpart[pc][c0 + j] = acc[j];
}

// ======================= fused single-dispatch kernel ========================
// 512 blocks x 1024 threads, 2 blocks/CU (all co-resident by construction:
// LDS 66.5KB, launch_bounds caps VGPR at 64 — round-10 counters demonstrated
// 2 blocks/CU resident with this exact footprint).
// cnt[0]: detect-done (target 64); cnt[1]: means-done (target 192);
// cnt[2],cnt[3]: detect c0/c1 accumulators. cnt zeroed by hipMemsetAsync.
__global__ __launch_bounds__(1024, 8) void fused_kernel(const void* __restrict__ cv,
                                                        const void* __restrict__ mv,
                                                        void* __restrict__ out,
                                                        int* __restrict__ cnt, int n) {
    __shared__ u32 kfrag[32][64][4];   // 32 KB: K frags / wm scratch / comb buf
    __shared__ u32 vfrag[32][64][4];   // 32 KB: V fragments
    __shared__ float slog[NV * P2];
    __shared__ int   sridx[TOPK];
    __shared__ int   smode;
    __shared__ int   bc[2];

    int bid = blockIdx.x, tid = threadIdx.x;
    int p = bid >> 3, m = bid & 7;

    // ---- phase A: detect sampling (blocks 0-63; bit-exact verified set) ----
    if (bid < 64) {
        if (tid < 2) bc[tid] = 0;
        __syncthreads();
        if (tid < 256) {
            int lim = n / 2;
            u32 r = ((u32)(tid + bid * 257) * 2654435761u);
            int j32 = (int)(r % (u32)lim);
            float a = fabsf(((const float*)cv)[j32]);
            bool c0 = (a >= 1e-4f && a <= 1e4f);
            int j16 = 2 * (int)((r >> 8) % (u32)lim);
            float b = fabsf(b2f(((const u16*)cv)[j16]));
            bool c1 = (b >= 1e-4f && b <= 1e4f);
            unsigned long long b0 = __ballot(c0);
            unsigned long long b1 = __ballot(c1);
            if ((tid & 63) == 0) {
                atomicAdd(&bc[0], __popcll(b0));
                atomicAdd(&bc[1], __popcll(b1));
            }
        }
        __syncthreads();
        if (tid == 0) {
            atomicAdd(&cnt[2], bc[0]);
            atomicAdd(&cnt[3], bc[1]);
            __threadfence();
            atomicAdd(&cnt[0], 1);
        }
    }
    // ---- wait for detect; compute mode from workspace atomics ----
    if (tid == 0) {
        while (atomicAdd(&cnt[0], 0) < 64) { __builtin_amdgcn_s_sleep(2); }
        int c0s = atomicAdd(&cnt[2], 0);
        int c1s = atomicAdd(&cnt[3], 0);
        const float T = 256.f * 64.f;
        float f0 = c0s / T, f1 = c1s / T;
        smode = (f1 >= 0.85f) ? 1 : ((f0 >= 0.80f) ? 0 : 2);
    }
    __syncthreads();
    int mode = smode;

    // ---- phase B: window means (blocks 0-191, one row each, 1024 threads) ----
    if (bid < 192) {
        float (*wmpart)[128] = (float(*)[128])&kfrag[0][0][0];
        if (mode == 0)      wm_row<0>(cv, mv, bid, tid, wmpart);
        else if (mode == 1) wm_row<1>(cv, mv, bid, tid, wmpart);
        else                wm_row<2>(cv, mv, bid, tid, wmpart);
        __syncthreads();
        if (tid < 128) {
            float s = 0.f;
#pragma unroll
            for (int k = 0; k < 64; ++k) s += wmpart[k][tid];
            g_means[bid * CC_ + tid] = s * (1.0f / 256.0f);
        }
        __threadfence();
        __syncthreads();
        if (tid == 0) atomicAdd(&cnt[1], 1);
    }
    // ---- wait for all means ----
    if (tid == 0) {
        while (atomicAdd(&cnt[1], 0) < 192) { __builtin_amdgcn_s_sleep(2); }
        __threadfence();
    }
    __syncthreads();

    // ---- phase C: window top-k (8 threads per window, 16 ch each) ----
    {
        int t  = tid >> 3;
        int cs = (tid & 7) << 4;
        const float4* qw = (const float4*)(g_means + p * CC_ + cs);
        const float4* kw = (const float4*)(g_means + (P2 + t) * CC_ + cs);
        float a = 0.f;
#pragma unroll
        for (int i = 0; i < 4; ++i) {
            float4 qv = qw[i], kv4 = kw[i];
            a += qv.x * kv4.x + qv.y * kv4.y + qv.z * kv4.z + qv.w * kv4.w;
        }
        a += __shfl_down(a, 4, 8);
        a += __shfl_down(a, 2, 8);
        a += __shfl_down(a, 1, 8);
        if ((tid & 7) == 0) slog[t] = a;
    }
    __syncthreads();
    if (tid == 0) {
#pragma unroll
        for (int k = 0; k < TOPK; ++k) {
            int best = 0; float bv = slog[0];
            for (int q2 = 1; q2 < NV * P2; ++q2)
                if (slog[q2] > bv) { bv = slog[q2]; best = q2; }
            sridx[k] = best;
            slog[best] = -3.0e38f;
        }
    }
    __syncthreads();

    int rwin[TOPK];
#pragma unroll
    for (int k = 0; k < TOPK; ++k) rwin[k] = sridx[k] & 127;

    if (mode == 0)      attn_body<0>(cv, mv, out, p, m, tid, kfrag, vfrag, rwin);
    else if (mode == 1) attn_body<1>(cv, mv, out, p, m, tid, kfrag, vfrag, rwin);
    else                attn_body<2>(cv, mv, out, p, m, tid, kfrag, vfrag, rwin);
}

// ===================== fallback 3-kernel path (round 10) =====================
__global__ void detect_sample(const void* __restrict__ cv, int n) {
    __shared__ int bc[2];
    int tid = threadIdx.x, k = blockIdx.x;
    if (tid < 2) bc[tid] = 0;
    __syncthreads();
    int lim = n / 2;
    u32 r = ((u32)(tid + k * 257) * 2654435761u);
    int j32 = (int)(r % (u32)lim);
    float a = fabsf(((const float*)cv)[j32]);
    bool c0 = (a >= 1e-4f && a <= 1e4f);
    int j16 = 2 * (int)((r >> 8) % (u32)lim);
    float b = fabsf(b2f(((const u16*)cv)[j16]));
    bool c1 = (b >= 1e-4f && b <= 1e4f);
    unsigned long long b0 = __ballot(c0);
    unsigned long long b1 = __ballot(c1);
    if ((tid & 63) == 0) {
        atomicAdd(&bc[0], __popcll(b0));
        atomicAdd(&bc[1], __popcll(b1));
    }
    __syncthreads();
    if (tid == 0) g_part[k] = make_int2(bc[0], bc[1]);
}

template<int MODE>
__device__ inline void wm_accum(const void* __restrict__ src, int voff, int jj, int ii,
                                int pc, int c0, float* __restrict__ acc) {
#pragma unroll
    for (int k = 0; k < 8; ++k) {
        int px = 8 * pc + k;
        int hh = px >> 4, ww = px & 15;
        int a = voff + ((jj * 16 + hh) * WW_ + ii * 16 + ww) * CC_ + c0;
        if (MODE == 0) {
            const float4* p4 = (const float4*)((const float*)src + a);
            float4 x = p4[0], y = p4[1];
            acc[0] += x.x; acc[1] += x.y; acc[2] += x.z; acc[3] += x.w;
            acc[4] += y.x; acc[5] += y.y; acc[6] += y.z; acc[7] += y.w;
        } else {
            uint4 v = *(const uint4*)((const u16*)src + a);
            u32 wd[4] = { v.x, v.y, v.z, v.w };
#pragma unroll
            for (int j = 0; j < 4; ++j) {
                u16 lo = (u16)(wd[j] & 0xFFFFu), hi = (u16)(wd[j] >> 16);
                acc[2 * j]     += (MODE == 1) ? b2f(lo) : h2f(lo);
                acc[2 * j + 1] += (MODE == 1) ? b2f(hi) : h2f(hi);
            }
        }
    }
}

__global__ __launch_bounds__(512) void win_mean_kernel2(const void* __restrict__ cv,
                                                        const void* __restrict__ mv) {
    __shared__ float part[32][128];
    __shared__ int   smode;
    int row = blockIdx.x, tid = threadIdx.x;
    if (tid == 0) smode = mode_from_parts();
    __syncthreads();
    int mode = smode;
    int o = tid & 15, pc = tid >> 4;
    const void* src; int voff = 0; int p;
    if (row < P2) { p = row; src = cv; }
    else { int r = row - P2; voff = (r >> 6) * HH_ * WW_ * CC_; p = r & 63; src = mv; }
    int jj = p >> 3, ii = p & 7;
    int c0 = 8 * o;
    float acc[8];
#pragma unroll
    for (int j = 0; j < 8; ++j) acc[j] = 0.f;
    if (mode == 0)      wm_accum<0>(src, voff, jj, ii, pc, c0, acc);
    else if (mode == 1) wm_accum<1>(src, voff, jj, ii, pc, c0, acc);
    else                wm_accum<2>(src, voff, jj, ii, pc, c0, acc);
#pragma unroll
    for (int j = 0; j < 8; ++j) part[pc][c0 + j] = acc[j];
    __syncthreads();
    if (tid < 128) {
        float s = 0.f;
#pragma unroll
        for (int k = 0; k < 32; ++k) s += part[k][tid];
        g_means[row * CC_ + tid] = s * (1.0f / 256.0f);
    }
}

__global__ __launch_bounds__(1024, 8) void attn_kernel(const void* __restrict__ cv,
                                                       const void* __restrict__ mv,
                                                       void* __restrict__ out) {
    __shared__ u32 kfrag[32][64][4];
    __shared__ u32 vfrag[32][64][4];
    __shared__ float slog[NV * P2];
    __shared__ int   sridx[TOPK];
    __shared__ int   smode;

    int bid = blockIdx.x;
    int p = bid >> 3, m = bid & 7;
    int tid = threadIdx.x;

    {
        int t  = tid >> 3;
        int cs = (tid & 7) << 4;
        const float4* qw = (const float4*)(g_means + p * CC_ + cs);
        const float4* kw = (const float4*)(g_means + (P2 + t) * CC_ + cs);
        float a = 0.f;
#pragma unroll
        for (int i = 0; i < 4; ++i) {
            float4 qv = qw[i], kv4 = kw[i];
            a += qv.x * kv4.x + qv.y * kv4.y + qv.z * kv4.z + qv.w * kv4.w;
        }
        a += __shfl_down(a, 4, 8);
        a += __shfl_down(a, 2, 8);
        a += __shfl_down(a, 1, 8);
        if ((tid & 7) == 0) slog[t] = a;
    }
    __syncthreads();
    if (tid == 0) {
        smode = mode_from_parts();
#pragma unroll
        for (int k = 0; k < TOPK; ++k) {
            int best = 0; float bv = slog[0];
            for (int q2 = 1; q2 < NV * P2; ++q2)
                if (slog[q2] > bv) { bv = slog[q2]; best = q2; }
            sridx[k] = best;
            slog[best] = -3.0e38f;
        }
    }
    __syncthreads();

    int mode = smode;
    int rwin[TOPK];
#pragma unroll
    for (int k = 0; k < TOPK; ++k) rwin[k] = sridx[k] & 127;

    if (mode == 0)      attn_body<0>(cv, mv, out, p, m, tid, kfrag, vfrag, rwin);
    else if (mode == 1) attn_body<1>(cv, mv, out, p, m, tid, kfrag, vfrag, rwin);
    else                attn_body<2>(cv, mv, out, p, m, tid, kfrag, vfrag, rwin);
}

extern "C" void kernel_launch(void* const* d_in, const int* in_sizes, int n_in,
                              void* d_out, int out_size, void* d_ws, size_t ws_size,
                              hipStream_t stream) {
    const void* cv = d_in[0];
    const void* mv = d_in[1];
    int n_cv = in_sizes[0];
    if (n_in >= 2 && in_sizes[0] > in_sizes[1]) { cv = d_in[1]; mv = d_in[0]; n_cv = in_sizes[1]; }
    (void)out_size;

    if (d_ws != nullptr && ws_size >= 64) {
        hipError_t e = hipMemsetAsync(d_ws, 0, 64, stream);
        (void)e;
        fused_kernel<<<P2 * NH, 1024, 0, stream>>>(cv, mv, d_out, (int*)d_ws, n_cv);
    } else {
        detect_sample<<<64, 256, 0, stream>>>(cv, n_cv);
        win_mean_kernel2<<<192, 512, 0, stream>>>(cv, mv);
        attn_kernel<<<P2 * NH, 1024, 0, stream>>>(cv, mv, d_out);
    }
}

// Round 13
// 126.952 us; speedup vs baseline: 1.6396x; 1.6396x over previous
//
#include <hip/hip_runtime.h>

#define HH_ 128
#define WW_ 128
#define CC_ 128
#define P2 64
#define W2 256
#define NH 8
#define CH 16
#define NV 2
#define TOPK 4
#define SCALE 0.08838834764831845f  // 128^-0.5
#define SCALE_L2E 0.1275216f        // SCALE * log2(e)
#define CLAMP_L2 28.8539f           // 20 * log2(e)

typedef unsigned short u16;
typedef unsigned int   u32;
typedef short s8v __attribute__((ext_vector_type(8)));   // 8 bf16 (4 VGPR)
typedef float f4  __attribute__((ext_vector_type(4)));

#if __has_builtin(__builtin_amdgcn_exp2f)
#define EXP2(x) __builtin_amdgcn_exp2f(x)
#else
#define EXP2(x) exp2f(x)
#endif

union FRAG { uint4 q; u32 u[4]; s8v v; };

__device__ float g_means[(P2 + NV * P2) * CC_];
__device__ int2  g_part[64];   // detector per-block partial counts

__device__ inline u16 f2b(float v) {
    union { float f; u32 u; } x; x.f = v;
    u32 r = x.u + 0x7FFFu + ((x.u >> 16) & 1u);
    return (u16)(r >> 16);
}
__device__ inline float b2f(u16 h) {
    union { u32 u; float f; } x; x.u = (u32)h << 16; return x.f;
}
__device__ inline float h2f(u16 h) {
    u32 s = (h >> 15) & 1u, e = (h >> 10) & 31u, m = h & 1023u;
    float v;
    if (e == 0)       v = m * 5.9604644775e-8f;
    else if (e == 31) v = 65504.f;
    else { union { u32 u; float f; } x; x.u = ((e + 112u) << 23) | (m << 13); v = x.f; }
    return s ? -v : v;
}
__device__ inline u16 f2h(float v) {
    union { float f; u32 u; } x; x.f = v;
    u32 s = (x.u >> 16) & 0x8000u;
    int  e = (int)((x.u >> 23) & 0xFF) - 112;
    u32  m = x.u & 0x7FFFFF;
    if (e >= 31) return (u16)(s | 0x7BFF);
    if (e <= 0) {
        if (e < -10) return (u16)s;
        m |= 0x800000u;
        int sh = 14 - e;
        u32 r = m >> sh, rem = m & ((1u << sh) - 1u), half = 1u << (sh - 1);
        if (rem > half || (rem == half && (r & 1))) r++;
        return (u16)(s | r);
    }
    u32 r = ((u32)e << 10) | (m >> 13), rem = m & 0x1FFFu;
    if (rem > 0x1000u || (rem == 0x1000u && (r & 1))) r++;
    return (u16)(s | r);
}

// ---- truncation-based bf16 split helpers ----
__device__ inline u32 pkhi(float a, float b) {
    union { float f; u32 u; } xa, xb; xa.f = a; xb.f = b;
    return (xa.u >> 16) | (xb.u & 0xFFFF0000u);
}
__device__ inline float hipart(float a) {
    union { float f; u32 u; } x; x.f = a; x.u &= 0xFFFF0000u; return x.f;
}

__device__ inline int mode_from_parts() {
    int c0 = 0, c1 = 0;
#pragma unroll 8
    for (int k = 0; k < 64; ++k) { int2 v = g_part[k]; c0 += v.x; c1 += v.y; }
    const float T = 256.f * 64.f;
    float f0 = c0 / T, f1 = c1 / T;
    if (f1 >= 0.85f) return 1;
    if (f0 >= 0.80f) return 0;
    return 2;
}

template<int MODE>
__device__ inline float decode1(const void* __restrict__ src, int off) {
    if (MODE == 0) return ((const float*)src)[off];
    u16 h = ((const u16*)src)[off];
    return (MODE == 1) ? b2f(h) : h2f(h);
}

template<int MODE>
__device__ inline float4 loadf4(const void* __restrict__ src, int off) {
    if (MODE == 0) return *(const float4*)((const float*)src + off);
    uint2 v = *(const uint2*)((const u16*)src + off);
    float4 r;
    if (MODE == 1) {
        r.x = b2f((u16)v.x); r.y = b2f((u16)(v.x >> 16));
        r.z = b2f((u16)v.y); r.w = b2f((u16)(v.y >> 16));
    } else {
        r.x = h2f((u16)v.x); r.y = h2f((u16)(v.x >> 16));
        r.z = h2f((u16)v.y); r.w = h2f((u16)(v.y >> 16));
    }
    return r;
}

template<int MODE>
__device__ inline void store4t(void* __restrict__ out, int off, const float* __restrict__ r) {
    if (MODE == 0) {
        *(float4*)((float*)out + off) = make_float4(r[0], r[1], r[2], r[3]);
    } else if (MODE == 1) {
        u32 w0 = (u32)f2b(r[0]) | ((u32)f2b(r[1]) << 16);
        u32 w1 = (u32)f2b(r[2]) | ((u32)f2b(r[3]) << 16);
        *(uint2*)((u16*)out + off) = make_uint2(w0, w1);
    } else {
        u32 w0 = (u32)f2h(r[0]) | ((u32)f2h(r[1]) << 16);
        u32 w1 = (u32)f2h(r[2]) | ((u32)f2h(r[3]) << 16);
        *(uint2*)((u16*)out + off) = make_uint2(w0, w1);
    }
}

// ---- detector sampling (verified structure, parallel) ----
__global__ void detect_sample(const void* __restrict__ cv, int n) {
    __shared__ int bc[2];
    int tid = threadIdx.x, k = blockIdx.x;
    if (tid < 2) bc[tid] = 0;
    __syncthreads();
    int lim = n / 2;
    u32 r = ((u32)(tid + k * 257) * 2654435761u);
    int j32 = (int)(r % (u32)lim);
    float a = fabsf(((const float*)cv)[j32]);
    bool c0 = (a >= 1e-4f && a <= 1e4f);
    int j16 = 2 * (int)((r >> 8) % (u32)lim);
    float b = fabsf(b2f(((const u16*)cv)[j16]));
    bool c1 = (b >= 1e-4f && b <= 1e4f);
    unsigned long long b0 = __ballot(c0);
    unsigned long long b1 = __ballot(c1);
    if ((tid & 63) == 0) {
        atomicAdd(&bc[0], __popcll(b0));
        atomicAdd(&bc[1], __popcll(b1));
    }
    __syncthreads();
    if (tid == 0) g_part[k] = make_int2(bc[0], bc[1]);
}

// ---- win_mean: vectorized 16B loads + LDS partial reduce (round-10 verified) ----
template<int MODE>
__device__ inline void wm_accum(const void* __restrict__ src, int voff, int jj, int ii,
                                int pc, int c0, float* __restrict__ acc) {
#pragma unroll
    for (int k = 0; k < 8; ++k) {
        int px = 8 * pc + k;
        int hh = px >> 4, ww = px & 15;
        int a = voff + ((jj * 16 + hh) * WW_ + ii * 16 + ww) * CC_ + c0;
        if (MODE == 0) {
            const float4* p4 = (const float4*)((const float*)src + a);
            float4 x = p4[0], y = p4[1];
            acc[0] += x.x; acc[1] += x.y; acc[2] += x.z; acc[3] += x.w;
            acc[4] += y.x; acc[5] += y.y; acc[6] += y.z; acc[7] += y.w;
        } else {
            uint4 v = *(const uint4*)((const u16*)src + a);
            u32 wd[4] = { v.x, v.y, v.z, v.w };
#pragma unroll
            for (int j = 0; j < 4; ++j) {
                u16 lo = (u16)(wd[j] & 0xFFFFu), hi = (u16)(wd[j] >> 16);
                acc[2 * j]     += (MODE == 1) ? b2f(lo) : h2f(lo);
                acc[2 * j + 1] += (MODE == 1) ? b2f(hi) : h2f(hi);
            }
        }
    }
}

__global__ __launch_bounds__(512) void win_mean_kernel(const void* __restrict__ cv,
                                                       const void* __restrict__ mv) {
    __shared__ float part[32][128];
    __shared__ int   smode;
    int row = blockIdx.x, tid = threadIdx.x;
    if (tid == 0) smode = mode_from_parts();
    __syncthreads();
    int mode = smode;
    int o = tid & 15, pc = tid >> 4;
    const void* src; int voff = 0; int p;
    if (row < P2) { p = row; src = cv; }
    else { int r = row - P2; voff = (r >> 6) * HH_ * WW_ * CC_; p = r & 63; src = mv; }
    int jj = p >> 3, ii = p & 7;
    int c0 = 8 * o;
    float acc[8];
#pragma unroll
    for (int j = 0; j < 8; ++j) acc[j] = 0.f;
    if (mode == 0)      wm_accum<0>(src, voff, jj, ii, pc, c0, acc);
    else if (mode == 1) wm_accum<1>(src, voff, jj, ii, pc, c0, acc);
    else                wm_accum<2>(src, voff, jj, ii, pc, c0, acc);
#pragma unroll
    for (int j = 0; j < 8; ++j) part[pc][c0 + j] = acc[j];
    __syncthreads();
    if (tid < 128) {
        float s = 0.f;
#pragma unroll
        for (int k = 0; k < 32; ++k) s += part[k][tid];
        g_means[row * CC_ + tid] = s * (1.0f / 256.0f);
    }
}

// ---- attention: producer-consumer wave specialization ----
// 512 blocks x 1024 threads. Waves 0-7 = compute (q-slot each, 2 qtiles,
// iterate all 4 windows); waves 8-15 = stage (fill next window's buffer).
// LDS double-buffer: buf[2] x 16 tiles (K+V packed split-bf16), 64 KB.
// Round r: compute reads buf[r&1] while stage fills buf[(r+1)&1]. One
// barrier per round -> stage latency hidden by different waves, not lockstep.
template<int MODE>
__device__ void attn_body(const void* __restrict__ cv, const void* __restrict__ mv,
                          void* __restrict__ out, int p, int m, int tid,
                          u32 (* __restrict__ kfrag)[16][64][4],
                          u32 (* __restrict__ vfrag)[16][64][4],
                          const int* __restrict__ rwin) {
    int jj = p >> 3, ii = p & 7;
    int wv = tid >> 6, l = tid & 63;
    int qs = wv & 7;
    int lg = l >> 4, lr = l & 15;

    // stage one (tile, lane) slot of window rwin[widx] into buffer b
    auto stage_slot = [&](int widx, int tl, int sl, int b) {
        int slg = sl >> 4, slr = sl & 15;
        int t = rwin[widx];
        int v = t >> 6, pp = t & 63;
        int jj2 = pp >> 3, ii2 = pp & 7;
        int wrow = (v * HH_ + jj2 * 16 + tl) * WW_ + ii2 * 16;
        {
            float4 kc = loadf4<MODE>(mv, (wrow + slr) * CC_ + m * CH + 4 * slg);
            FRAG kf;
            kf.u[0] = pkhi(kc.x, kc.y);
            kf.u[1] = pkhi(kc.z, kc.w);
            kf.u[2] = pkhi(kc.x - hipart(kc.x), kc.y - hipart(kc.y));
            kf.u[3] = pkhi(kc.z - hipart(kc.z), kc.w - hipart(kc.w));
            *(uint4*)&kfrag[b][tl][sl][0] = kf.q;
        }
        {
            int a = (wrow + 4 * slg) * CC_ + m * CH + slr;
            float v0 = decode1<MODE>(mv, a);
            float v1 = decode1<MODE>(mv, a + CC_);
            float v2 = decode1<MODE>(mv, a + 2 * CC_);
            float v3 = decode1<MODE>(mv, a + 3 * CC_);
            FRAG vf;
            vf.u[0] = pkhi(v0, v1);
            vf.u[1] = pkhi(v2, v3);
            vf.u[2] = pkhi(v0 - hipart(v0), v1 - hipart(v1));
            vf.u[3] = pkhi(v2 - hipart(v2), v3 - hipart(v3));
            *(uint4*)&vfrag[b][tl][sl][0] = vf.q;
        }
    };

    // Q fragments (compute waves only), prescaled by SCALE*log2e
    FRAG qf1[2], qf2[2];
    if (wv < 8) {
#pragma unroll
        for (int qi = 0; qi < 2; ++qi) {
            int qrow = qs * 32 + qi * 16 + lr;
            int hh = qrow >> 4, ww = qrow & 15;
            int pix = (jj * 16 + hh) * WW_ + (ii * 16 + ww);
            float4 qv = loadf4<MODE>(cv, pix * CC_ + m * CH + 4 * lg);
            float q0 = qv.x * SCALE_L2E, q1 = qv.y * SCALE_L2E;
            float q2 = qv.z * SCALE_L2E, q3 = qv.w * SCALE_L2E;
            u32 h01 = pkhi(q0, q1), h23 = pkhi(q2, q3);
            u32 l01 = pkhi(q0 - hipart(q0), q1 - hipart(q1));
            u32 l23 = pkhi(q2 - hipart(q2), q3 - hipart(q3));
            qf1[qi].u[0] = h01; qf1[qi].u[1] = h23; qf1[qi].u[2] = l01; qf1[qi].u[3] = l23;
            qf2[qi].u[0] = l01; qf2[qi].u[1] = l23; qf2[qi].u[2] = h01; qf2[qi].u[3] = h23;
        }
    }

    // initial fill: ALL 16 waves stage window 0 into buf 0 (1 slot each)
    stage_slot(0, tid >> 6, tid & 63, 0);
    __syncthreads();

    f4 Oacc0 = {0.f, 0.f, 0.f, 0.f};
    f4 Oacc1 = {0.f, 0.f, 0.f, 0.f};
    float lp0 = 0.f, lp1 = 0.f;

#pragma unroll 1
    for (int r = 0; r < 4; ++r) {
        if (wv >= 8) {
            // producer: fill next window into the other buffer (2 slots/thread)
            if (r < 3) {
                int t2 = tid - 512;
                stage_slot(r + 1, t2 >> 6, t2 & 63, (r + 1) & 1);
                int t3 = t2 + 512;
                stage_slot(r + 1, t3 >> 6, t3 & 63, (r + 1) & 1);
            }
        } else {
            // consumer: 16 tiles of window r from buf[r&1]
            const uint4* kp = (const uint4*)&kfrag[r & 1][0][0][0] + l;
            const uint4* vp = (const uint4*)&vfrag[r & 1][0][0][0] + l;
#pragma unroll 4
            for (int tl = 0; tl < 16; ++tl) {
                FRAG kf, vf;
                kf.q = kp[tl * 64];
                vf.q = vp[tl * 64];
                // qtile 0
                {
                    f4 sc = {0.f, 0.f, 0.f, 0.f};
                    sc = __builtin_amdgcn_mfma_f32_16x16x32_bf16(kf.v, qf1[0].v, sc, 0, 0, 0);
                    sc = __builtin_amdgcn_mfma_f32_16x16x32_bf16(kf.v, qf2[0].v, sc, 0, 0, 0);
                    float pe0 = EXP2(fminf(sc[0], CLAMP_L2));
                    float pe1 = EXP2(fminf(sc[1], CLAMP_L2));
                    float pe2 = EXP2(fminf(sc[2], CLAMP_L2));
                    float pe3 = EXP2(fminf(sc[3], CLAMP_L2));
                    lp0 += (hipart(pe0) + hipart(pe1)) + (hipart(pe2) + hipart(pe3));
                    FRAG pf;
                    pf.u[0] = pkhi(pe0, pe1);
                    pf.u[1] = pkhi(pe2, pe3);
                    pf.u[2] = pf.u[0];
                    pf.u[3] = pf.u[1];
                    Oacc0 = __builtin_amdgcn_mfma_f32_16x16x32_bf16(vf.v, pf.v, Oacc0, 0, 0, 0);
                }
                // qtile 1
                {
                    f4 sc = {0.f, 0.f, 0.f, 0.f};
                    sc = __builtin_amdgcn_mfma_f32_16x16x32_bf16(kf.v, qf1[1].v, sc, 0, 0, 0);
                    sc = __builtin_amdgcn_mfma_f32_16x16x32_bf16(kf.v, qf2[1].v, sc, 0, 0, 0);
                    float pe0 = EXP2(fminf(sc[0], CLAMP_L2));
                    float pe1 = EXP2(fminf(sc[1], CLAMP_L2));
                    float pe2 = EXP2(fminf(sc[2], CLAMP_L2));
                    float pe3 = EXP2(fminf(sc[3], CLAMP_L2));
                    lp1 += (hipart(pe0) + hipart(pe1)) + (hipart(pe2) + hipart(pe3));
                    FRAG pf;
                    pf.u[0] = pkhi(pe0, pe1);
                    pf.u[1] = pkhi(pe2, pe3);
                    pf.u[2] = pf.u[0];
                    pf.u[3] = pf.u[1];
                    Oacc1 = __builtin_amdgcn_mfma_f32_16x16x32_bf16(vf.v, pf.v, Oacc1, 0, 0, 0);
                }
            }
        }
        __syncthreads();
    }

    // epilogue: compute waves reduce l across lane-groups, normalize, store
    if (wv < 8) {
#pragma unroll
        for (int qi = 0; qi < 2; ++qi) {
            float lt = (qi == 0) ? lp0 : lp1;
            lt += __shfl_xor(lt, 16);
            lt += __shfl_xor(lt, 32);
            float inv = 1.0f / fmaxf(lt, 1e-30f);
            f4 Oa = (qi == 0) ? Oacc0 : Oacc1;
            float res[4];
#pragma unroll
            for (int r = 0; r < 4; ++r)
                res[r] = fminf(fmaxf(Oa[r] * inv, -1000.f), 1000.f);
            int qrow = qs * 32 + qi * 16 + lr;
            int hh = qrow >> 4, ww = qrow & 15;
            int pix = (jj * 16 + hh) * WW_ + (ii * 16 + ww);
            store4t<MODE>(out, pix * CC_ + m * CH + 4 * lg, res);
        }
    }
}

__global__ __launch_bounds__(1024, 8) void attn_kernel(const void* __restrict__ cv,
                                                       const void* __restrict__ mv,
                                                       void* __restrict__ out) {
    __shared__ u32 kfrag[2][16][64][4];   // 32 KB: double-buffered K fragments
    __shared__ u32 vfrag[2][16][64][4];   // 32 KB: double-buffered V fragments
    __shared__ float slog[NV * P2];
    __shared__ int   sridx[TOPK];
    __shared__ int   smode;

    int bid = blockIdx.x;
    int p = bid >> 3, m = bid & 7;
    int tid = threadIdx.x;

    // phase 1: window-level top-k (8 threads per window, 16 ch each)
    {
        int t  = tid >> 3;
        int cs = (tid & 7) << 4;
        const float4* qw = (const float4*)(g_means + p * CC_ + cs);
        const float4* kw = (const float4*)(g_means + (P2 + t) * CC_ + cs);
        float a = 0.f;
#pragma unroll
        for (int i = 0; i < 4; ++i) {
            float4 qv = qw[i], kv4 = kw[i];
            a += qv.x * kv4.x + qv.y * kv4.y + qv.z * kv4.z + qv.w * kv4.w;
        }
        a += __shfl_down(a, 4, 8);
        a += __shfl_down(a, 2, 8);
        a += __shfl_down(a, 1, 8);
        if ((tid & 7) == 0) slog[t] = a;
    }
    __syncthreads();
    if (tid == 0) {
        smode = mode_from_parts();
#pragma unroll
        for (int k = 0; k < TOPK; ++k) {
            int best = 0; float bv = slog[0];
            for (int q2 = 1; q2 < NV * P2; ++q2)
                if (slog[q2] > bv) { bv = slog[q2]; best = q2; }
            sridx[k] = best;
            slog[best] = -3.0e38f;
        }
    }
    __syncthreads();

    int mode = smode;
    int rwin[TOPK];
#pragma unroll
    for (int k = 0; k < TOPK; ++k) rwin[k] = sridx[k] & 127;

    if (mode == 0)      attn_body<0>(cv, mv, out, p, m, tid, kfrag, vfrag, rwin);
    else if (mode == 1) attn_body<1>(cv, mv, out, p, m, tid, kfrag, vfrag, rwin);
    else                attn_body<2>(cv, mv, out, p, m, tid, kfrag, vfrag, rwin);
}

extern "C" void kernel_launch(void* const* d_in, const int* in_sizes, int n_in,
                              void* d_out, int out_size, void* d_ws, size_t ws_size,
                              hipStream_t stream) {
    const void* cv = d_in[0];
    const void* mv = d_in[1];
    int n_cv = in_sizes[0];
    if (n_in >= 2 && in_sizes[0] > in_sizes[1]) { cv = d_in[1]; mv = d_in[0]; n_cv = in_sizes[1]; }
    (void)d_ws; (void)ws_size; (void)out_size;

    detect_sample<<<64, 256, 0, stream>>>(cv, n_cv);
    win_mean_kernel<<<192, 512, 0, stream>>>(cv, mv);
    attn_kernel<<<P2 * NH, 1024, 0, stream>>>(cv, mv, d_out);
}